// Round 5
// baseline (1518.596 us; speedup 1.0000x reference)
//
#include <hip/hip_runtime.h>
#include <cstdint>
#include <cstddef>

// I/O fp32; intermediates bf16; math fp32.
typedef __bf16 bf16x8 __attribute__((ext_vector_type(8)));
typedef float  f32x4  __attribute__((ext_vector_type(4)));

__device__ __forceinline__ float bf2f(unsigned short u) {
  union { unsigned int u; float f; } v; v.u = ((unsigned int)u) << 16; return v.f;
}
__device__ __forceinline__ unsigned short f2bf(float f) {
  union { float f; unsigned int u; } v; v.f = f;
  return (unsigned short)((v.u + 0x7fffu + ((v.u >> 16) & 1u)) >> 16);
}
__device__ __forceinline__ void g2lds16(const void* g, void* l) {
  __builtin_amdgcn_global_load_lds((__attribute__((address_space(1))) void*)g,
                                   (__attribute__((address_space(3))) void*)l,
                                   16, 0, 0);
}

// ---------- GEMM: C[M,N](bf16) = A[M,K](bf16) * BT[N,K](bf16)^T + bias(fp32) ----------
// BK=64, 16B-chunk XOR swizzle (chunk ^= row&7) to spread LDS banks.
// EPI: 0 = +bias, 1 = +bias then gelu(tanh-approx)
template<int EPI>
__global__ __launch_bounds__(256) void gemm_bt(
    const unsigned short* __restrict__ A, const unsigned short* __restrict__ BT,
    const float* __restrict__ bias, unsigned short* __restrict__ C,
    int M, int N, int K)
{
  __shared__ __align__(16) unsigned short ldsA[128 * 64];
  __shared__ __align__(16) unsigned short ldsB[128 * 64];
  const int tid  = threadIdx.x;
  const int wave = tid >> 6;
  const int lane = tid & 63;
  const int bm = blockIdx.y, bn = blockIdx.x;
  const int lm = lane & 15, quad = lane >> 4;
  const int wm = (wave >> 1) * 64, wn = (wave & 1) * 64;

  f32x4 acc[4][4];
#pragma unroll
  for (int i = 0; i < 4; i++)
#pragma unroll
    for (int j = 0; j < 4; j++) acc[i][j] = {0.f, 0.f, 0.f, 0.f};

  // staging: each g2lds fills 8 rows x 64 shorts (1 KiB) per wave; 4 issues cover 32 rows.
  const int l8 = lane >> 3;            // row within 8-row group
  const int sw = (lane & 7) ^ l8;      // swizzled 16B-chunk index
  const unsigned short* pAb = A  + (size_t)(bm * 128 + wave * 8 + l8) * K + sw * 8;
  const unsigned short* pBb = BT + (size_t)(bn * 128 + wave * 8 + l8) * K + sw * 8;
  unsigned short* dAb = &ldsA[(wave * 8) * 64];
  unsigned short* dBb = &ldsB[(wave * 8) * 64];

  for (int k0 = 0; k0 < K; k0 += 64) {
#pragma unroll
    for (int i = 0; i < 4; i++) {
      g2lds16(pAb + (size_t)i * 32 * K + k0, dAb + i * 32 * 64);
      g2lds16(pBb + (size_t)i * 32 * K + k0, dBb + i * 32 * 64);
    }
    __syncthreads();
    bf16x8 af[2][4], bfr[2][4];
#pragma unroll
    for (int kc = 0; kc < 2; kc++) {
      const int cs = ((kc * 4 + quad) ^ (lm & 7)) * 8;
#pragma unroll
      for (int i = 0; i < 4; i++) {
        af[kc][i]  = *reinterpret_cast<const bf16x8*>(&ldsA[(wm + i * 16 + lm) * 64 + cs]);
        bfr[kc][i] = *reinterpret_cast<const bf16x8*>(&ldsB[(wn + i * 16 + lm) * 64 + cs]);
      }
    }
#pragma unroll
    for (int kc = 0; kc < 2; kc++)
#pragma unroll
      for (int i = 0; i < 4; i++)
#pragma unroll
        for (int j = 0; j < 4; j++)
          acc[i][j] = __builtin_amdgcn_mfma_f32_16x16x32_bf16(af[kc][i], bfr[kc][j], acc[i][j], 0, 0, 0);
    __syncthreads();
  }

#pragma unroll
  for (int i = 0; i < 4; i++) {
#pragma unroll
    for (int j = 0; j < 4; j++) {
#pragma unroll
      for (int r = 0; r < 4; r++) {
        int row = bm * 128 + wm + i * 16 + quad * 4 + r;
        int col = bn * 128 + wn + j * 16 + lm;
        float v = acc[i][j][r];
        if (bias) v += bias[col];
        if (EPI == 1) {
          float xx = v;
          float u = 1.5957691216057308f * (xx + 0.044715f * xx * xx * xx);
          v = xx / (1.f + __expf(-u));
        }
        C[(size_t)row * N + col] = f2bf(v);
      }
    }
  }
}

// ---------- weight transpose + cast: W[K,N] fp32 -> WT[N,K] bf16 ----------
__global__ __launch_bounds__(256) void transpose_cast(
    const float* __restrict__ W, unsigned short* __restrict__ WT, int K, int N)
{
  __shared__ float t[32][33];
  int bx = blockIdx.x, by = blockIdx.y;
  int tx = threadIdx.x & 31, ty = threadIdx.x >> 5;
#pragma unroll
  for (int j = 0; j < 4; j++)
    t[ty + j * 8][tx] = W[(size_t)(by * 32 + ty + j * 8) * N + bx * 32 + tx];
  __syncthreads();
#pragma unroll
  for (int j = 0; j < 4; j++)
    WT[(size_t)(bx * 32 + ty + j * 8) * K + by * 32 + tx] = f2bf(t[tx][ty + j * 8]);
}

// ---------- fused qkv bias: [q_b | 0 | v_b] fp32[1536] ----------
__global__ __launch_bounds__(256) void fused_bias(
    const float* __restrict__ qb, const float* __restrict__ vb, float* __restrict__ fb)
{
  int i = blockIdx.x * 256 + threadIdx.x;
  if (i >= 1536) return;
  float v = 0.f;
  if (i < 512) v = qb[i];
  else if (i >= 1024) v = vb[i - 1024];
  fb[i] = v;
}

// ---------- shift + window partition + cast ----------
__global__ __launch_bounds__(256) void shift_part(
    const float* __restrict__ x, unsigned short* __restrict__ xw)
{
  int t = blockIdx.x * 256 + threadIdx.x;
  int row = t >> 7;
  int c = (t & 127) * 4;
  int b = row >> 12, rw_ = row & 4095;
  int wi = rw_ >> 6, p = rw_ & 63;
  int hh = (((wi >> 3) * 8 + (p >> 3)) + 4) & 63;
  int ww = (((wi & 7) * 8 + (p & 7)) + 4) & 63;
  const float4 v = *(const float4*)&x[(((size_t)b * 4096) + hh * 64 + ww) * 512 + c];
  ushort4 o;
  o.x = f2bf(v.x); o.y = f2bf(v.y); o.z = f2bf(v.z); o.w = f2bf(v.w);
  *(ushort4*)&xw[(size_t)row * 512 + c] = o;
}

// ---------- CPB table: tbl16[225][16] = 16*sigmoid(mlp(rel)) fp32 ----------
__device__ __forceinline__ float relsc(int v) {
  float a = fabsf((float)v) * (8.0f / 7.0f);
  float r = log2f(a + 1.f) * (1.f / 3.f);
  return v < 0 ? -r : r;
}
__global__ __launch_bounds__(512) void cpb_kernel(
    const float* __restrict__ w1, const float* __restrict__ b1,
    const float* __restrict__ w2, const float* __restrict__ b2, float* __restrict__ tbl)
{
  __shared__ float hid[512];
  int p = blockIdx.x;
  int i = p / 15, j = p % 15;
  float fr = relsc(i - 7);
  float fc = relsc(j - 7);
  int t = threadIdx.x;
  float hv = fc * w1[t] + fr * w1[512 + t] + b1[t];
  hid[t] = fmaxf(hv, 0.f);
  __syncthreads();
  if (t < 16) {
    float s = b2[t];
    for (int u = 0; u < 512; u++) s += hid[u] * w2[u * 16 + t];
    tbl[p * 16 + t] = 16.f / (1.f + __expf(-s));   // pre-sigmoided bias
  }
}

// ---------- MFMA attention: 2048 blocks = (window, head-half); 8 heads per block ----------
__global__ __launch_bounds__(256) void attn_mfma(
    const unsigned short* __restrict__ qkv, const float* __restrict__ tau,
    const float* __restrict__ tbl16, unsigned short* __restrict__ Om)
{
  __shared__ __align__(16) unsigned short Qs[64 * 32];
  __shared__ __align__(16) unsigned short Ks[64 * 32];
  __shared__ __align__(16) unsigned short VT[32 * 72];   // V^T, padded stride 72
  __shared__ __align__(16) unsigned short Pb[64 * 72];   // P, padded stride 72
  __shared__ float qns[64];
  __shared__ float tblh[225];
  __shared__ int scode[64];

  const int tid = threadIdx.x;
  const int wave = tid >> 6, lane = tid & 63;
  const int lm = lane & 15, quad = lane >> 4;
  const int w = blockIdx.x >> 1;
  const int hbase = (blockIdx.x & 1) * 8;
  const int wi = w & 63, wr = wi >> 3, wc = wi & 7;
  const size_t wbase = (size_t)w * 64 * 1536;

  if (tid < 64) {
    int p = tid;
    int rp = wr * 8 + (p >> 3), cp = wc * 8 + (p & 7);
    scode[p] = (rp < 56 ? 0 : (rp < 60 ? 1 : 2)) * 3 + (cp < 56 ? 0 : (cp < 60 ? 1 : 2));
  }

  const int srow = wave * 16 + (lane >> 2);
  const int scol = (lane & 3) * 8;
  unsigned short* qdst = &Qs[wave * 16 * 32];
  unsigned short* kdst = &Ks[wave * 16 * 32];
  const int vq = tid & 63, vd0 = (tid >> 6) * 8;

  for (int hh = 0; hh < 8; hh++) {
    const int h = hbase + hh;
    const size_t rbase = wbase + (size_t)srow * 1536 + h * 32 + scol;
    g2lds16(qkv + rbase, qdst);                 // Q cols [0,512)
    g2lds16(qkv + rbase + 512, kdst);           // K cols [512,1024)
    // V^T direct: vector global read, conflict-free column writes
    uint4 vv = *(const uint4*)&qkv[wbase + (size_t)vq * 1536 + 1024 + h * 32 + vd0];
    const unsigned short* vs = (const unsigned short*)&vv;
#pragma unroll
    for (int j = 0; j < 8; j++) VT[(vd0 + j) * 72 + vq] = vs[j];
    if (tid < 225) tblh[tid] = tbl16[tid * 16 + h];
    __syncthreads();

    // ---- fragments + norms from fragments (no conflicted LDS loops) ----
    bf16x8 af = *reinterpret_cast<const bf16x8*>(&Qs[(wave * 16 + lm) * 32 + quad * 8]);
    {
      union { bf16x8 v; unsigned short s[8]; } ua; ua.v = af;
      float qss = 0.f;
#pragma unroll
      for (int j = 0; j < 8; j++) { float t = bf2f(ua.s[j]); qss += t * t; }
      qss += __shfl_xor(qss, 16, 64);
      qss += __shfl_xor(qss, 32, 64);
      qns[wave * 16 + lm] = sqrtf(qss);   // same-wave LDS, no barrier needed
    }
    f32x4 accS[4];
    float kn_r[4];
#pragma unroll
    for (int ni = 0; ni < 4; ni++) {
      bf16x8 bfr = *reinterpret_cast<const bf16x8*>(&Ks[(ni * 16 + lm) * 32 + quad * 8]);
      union { bf16x8 v; unsigned short s[8]; } ub; ub.v = bfr;
      float kss = 0.f;
#pragma unroll
      for (int j = 0; j < 8; j++) { float t = bf2f(ub.s[j]); kss += t * t; }
      kss += __shfl_xor(kss, 16, 64);
      kss += __shfl_xor(kss, 32, 64);
      kn_r[ni] = sqrtf(kss);              // norm of K row ni*16+lm
      f32x4 z = {0.f, 0.f, 0.f, 0.f};
      accS[ni] = __builtin_amdgcn_mfma_f32_16x16x32_bf16(af, bfr, z, 0, 0, 0);
    }

    // ---- epilogue + softmax (C-layout: col=lane&15 -> key q, row=quad*4+r -> query p) ----
    const float scale = fmaxf(tau[h] + 2.302585092994046f, 0.01f);
#pragma unroll
    for (int r = 0; r < 4; r++) {
      int p = wave * 16 + quad * 4 + r;
      float qnp = qns[p];
      int cp = scode[p];
      float sv[4];
#pragma unroll
      for (int ni = 0; ni < 4; ni++) {
        int q = ni * 16 + lm;
        float denom = fmaxf(qnp * kn_r[ni], 1e-6f);
        int dr = (p >> 3) - (q >> 3) + 7, dc = (p & 7) - (q & 7) + 7;
        float bv = tblh[dr * 15 + dc];    // already 16*sigmoid
        float mask = (cp == scode[q]) ? 0.f : -100.f;
        sv[ni] = accS[ni][r] / denom * scale + bv + mask;
      }
      float m = fmaxf(fmaxf(sv[0], sv[1]), fmaxf(sv[2], sv[3]));
#pragma unroll
      for (int off = 1; off < 16; off <<= 1) m = fmaxf(m, __shfl_xor(m, off, 64));
      float s = 0;
#pragma unroll
      for (int ni = 0; ni < 4; ni++) { sv[ni] = __expf(sv[ni] - m); s += sv[ni]; }
#pragma unroll
      for (int off = 1; off < 16; off <<= 1) s += __shfl_xor(s, off, 64);
      float inv = 1.f / s;
#pragma unroll
      for (int ni = 0; ni < 4; ni++)
        Pb[p * 72 + ni * 16 + lm] = f2bf(sv[ni] * inv);
    }
    // no barrier: PV's A-tile uses only this wave's own P strip (same-wave LDS RAW)

    // ---- PV: O strip = P(16x64) x V(64x32) via V^T ----
    bf16x8 paf[2];
#pragma unroll
    for (int kc = 0; kc < 2; kc++)
      paf[kc] = *reinterpret_cast<const bf16x8*>(&Pb[(wave * 16 + lm) * 72 + kc * 32 + quad * 8]);
    f32x4 accO[2];
#pragma unroll
    for (int n2 = 0; n2 < 2; n2++) {
      f32x4 z = {0.f, 0.f, 0.f, 0.f};
#pragma unroll
      for (int kc = 0; kc < 2; kc++) {
        bf16x8 vb = *reinterpret_cast<const bf16x8*>(&VT[(n2 * 16 + lm) * 72 + kc * 32 + quad * 8]);
        z = __builtin_amdgcn_mfma_f32_16x16x32_bf16(paf[kc], vb, z, 0, 0, 0);
      }
      accO[n2] = z;
    }
#pragma unroll
    for (int n2 = 0; n2 < 2; n2++)
#pragma unroll
      for (int r = 0; r < 4; r++) {
        int p = wave * 16 + quad * 4 + r;
        Om[((size_t)w * 64 + p) * 512 + h * 32 + n2 * 16 + lm] = f2bf(accO[n2][r]);
      }
    __syncthreads();   // before next head restages Qs/Ks/VT/tblh
  }
}

// ---------- LN1: un-shift gather + layernorm + residual -> x1 bf16 ----------
__global__ __launch_bounds__(256) void ln1_kernel(
    const float* __restrict__ x, const unsigned short* __restrict__ proj,
    const float* __restrict__ g, const float* __restrict__ b,
    unsigned short* __restrict__ x1b)
{
  __shared__ float r1[4], r2[4], stats[2];
  int tkn = blockIdx.x;
  int bb = tkn >> 12, s = tkn & 4095;
  int h_ = s >> 6, w_ = s & 63;
  int r = (h_ + 60) & 63, cc = (w_ + 60) & 63;
  int wi = (r >> 3) * 8 + (cc >> 3);
  int p = (r & 7) * 8 + (cc & 7);
  size_t src = ((size_t)bb * 4096 + wi * 64 + p) * 512;
  int c = threadIdx.x * 2;
  unsigned int pv = *(const unsigned int*)&proj[src + c];
  float v0 = bf2f((unsigned short)(pv & 0xffff)), v1 = bf2f((unsigned short)(pv >> 16));
  float ls = v0 + v1, lq = v0 * v0 + v1 * v1;
  for (int off = 32; off > 0; off >>= 1) {
    ls += __shfl_down(ls, off, 64);
    lq += __shfl_down(lq, off, 64);
  }
  int wv = threadIdx.x >> 6, ln = threadIdx.x & 63;
  if (ln == 0) { r1[wv] = ls; r2[wv] = lq; }
  __syncthreads();
  if (threadIdx.x == 0) {
    float S1 = r1[0] + r1[1] + r1[2] + r1[3];
    float S2 = r2[0] + r2[1] + r2[2] + r2[3];
    float mean = S1 * (1.f / 512.f);
    float var = S2 * (1.f / 512.f) - mean * mean;
    stats[0] = mean; stats[1] = rsqrtf(var + 1e-6f);
  }
  __syncthreads();
  float mean = stats[0], rstd = stats[1];
  size_t o = (size_t)tkn * 512 + c;
  float2 xv = *(const float2*)&x[o];
  float y0 = (v0 - mean) * rstd * g[c] + b[c] + xv.x;
  float y1 = (v1 - mean) * rstd * g[c + 1] + b[c + 1] + xv.y;
  unsigned int ov = (unsigned int)f2bf(y0) | ((unsigned int)f2bf(y1) << 16);
  *(unsigned int*)&x1b[o] = ov;
}

// ---------- LN2 + residual -> out fp32 ----------
__global__ __launch_bounds__(256) void ln2_kernel(
    const unsigned short* __restrict__ x1b, const unsigned short* __restrict__ h2,
    const float* __restrict__ g, const float* __restrict__ b,
    float* __restrict__ out)
{
  __shared__ float r1[4], r2[4], stats[2];
  int tkn = blockIdx.x;
  int c = threadIdx.x * 2;
  size_t o = (size_t)tkn * 512 + c;
  unsigned int hv = *(const unsigned int*)&h2[o];
  float v0 = bf2f((unsigned short)(hv & 0xffff)), v1 = bf2f((unsigned short)(hv >> 16));
  float ls = v0 + v1, lq = v0 * v0 + v1 * v1;
  for (int off = 32; off > 0; off >>= 1) {
    ls += __shfl_down(ls, off, 64);
    lq += __shfl_down(lq, off, 64);
  }
  int wv = threadIdx.x >> 6, ln = threadIdx.x & 63;
  if (ln == 0) { r1[wv] = ls; r2[wv] = lq; }
  __syncthreads();
  if (threadIdx.x == 0) {
    float S1 = r1[0] + r1[1] + r1[2] + r1[3];
    float S2 = r2[0] + r2[1] + r2[2] + r2[3];
    float mean = S1 * (1.f / 512.f);
    float var = S2 * (1.f / 512.f) - mean * mean;
    stats[0] = mean; stats[1] = rsqrtf(var + 1e-6f);
  }
  __syncthreads();
  float mean = stats[0], rstd = stats[1];
  unsigned int xv = *(const unsigned int*)&x1b[o];
  float x0 = bf2f((unsigned short)(xv & 0xffff)), x1 = bf2f((unsigned short)(xv >> 16));
  float2 ov;
  ov.x = x0 + (v0 - mean) * rstd * g[c] + b[c];
  ov.y = x1 + (v1 - mean) * rstd * g[c + 1] + b[c + 1];
  *(float2*)&out[o] = ov;
}

// ---------- launcher ----------
extern "C" void kernel_launch(void* const* d_in, const int* in_sizes, int n_in,
                              void* d_out, int out_size, void* d_ws, size_t ws_size,
                              hipStream_t stream) {
  const float* x      = (const float*)d_in[0];
  const float* q_w    = (const float*)d_in[1];
  const float* q_b    = (const float*)d_in[2];
  const float* k_w    = (const float*)d_in[3];
  const float* v_w    = (const float*)d_in[4];
  const float* v_b    = (const float*)d_in[5];
  const float* proj_w = (const float*)d_in[6];
  const float* proj_b = (const float*)d_in[7];
  const float* tau    = (const float*)d_in[8];
  const float* cpb_w1 = (const float*)d_in[9];
  const float* cpb_b1 = (const float*)d_in[10];
  const float* cpb_w2 = (const float*)d_in[11];
  const float* cpb_b2 = (const float*)d_in[12];
  const float* n1g    = (const float*)d_in[13];
  const float* n1b    = (const float*)d_in[14];
  const float* n2g    = (const float*)d_in[15];
  const float* n2b    = (const float*)d_in[16];
  const float* mlp_w1 = (const float*)d_in[17];
  const float* mlp_b1 = (const float*)d_in[18];
  const float* mlp_w2 = (const float*)d_in[19];
  const float* mlp_b2 = (const float*)d_in[20];
  float* out = (float*)d_out;
  char* ws = (char*)d_ws;

  // workspace (~326 MiB):
  //   [0,64)    xw -> Obuf
  //   [64,256)  qkv (65536 x 1536 bf16); after attn: x1b [64,128), hbuf [128,256)
  //   [256,320) projb -> h2b
  //   [320,..)  weights: qkvT 1.5M | pwT 0.5M | m1T 2M | m2T 2M | tbl 16K | fbias 8K
  const size_t MB = 1048576;
  unsigned short* xw    = (unsigned short*)(ws + 0 * MB);
  unsigned short* Obuf  = (unsigned short*)(ws + 0 * MB);
  unsigned short* qkv   = (unsigned short*)(ws + 64 * MB);
  unsigned short* x1b   = (unsigned short*)(ws + 64 * MB);
  unsigned short* hbuf  = (unsigned short*)(ws + 128 * MB);
  unsigned short* projb = (unsigned short*)(ws + 256 * MB);
  unsigned short* h2b   = (unsigned short*)(ws + 256 * MB);
  char* w0 = ws + 320 * MB;
  unsigned short* qkvT = (unsigned short*)(w0);                 // 1536x512
  unsigned short* pwT  = (unsigned short*)(w0 + 0x180000);
  unsigned short* m1T  = (unsigned short*)(w0 + 0x200000);
  unsigned short* m2T  = (unsigned short*)(w0 + 0x400000);
  float* tbl           = (float*)         (w0 + 0x600000);
  float* fbias         = (float*)         (w0 + 0x610000);

  transpose_cast<<<dim3(16, 16), 256, 0, stream>>>(q_w,    qkvT,              512, 512);
  transpose_cast<<<dim3(16, 16), 256, 0, stream>>>(k_w,    qkvT + 512 * 512,  512, 512);
  transpose_cast<<<dim3(16, 16), 256, 0, stream>>>(v_w,    qkvT + 1024 * 512, 512, 512);
  transpose_cast<<<dim3(16, 16), 256, 0, stream>>>(proj_w, pwT, 512, 512);
  transpose_cast<<<dim3(64, 16), 256, 0, stream>>>(mlp_w1, m1T, 512, 2048);
  transpose_cast<<<dim3(16, 64), 256, 0, stream>>>(mlp_w2, m2T, 2048, 512);
  fused_bias<<<6, 256, 0, stream>>>(q_b, v_b, fbias);
  cpb_kernel<<<225, 512, 0, stream>>>(cpb_w1, cpb_b1, cpb_w2, cpb_b2, tbl);
  shift_part<<<32768, 256, 0, stream>>>(x, xw);
  // fused QKV GEMM: N=1536
  gemm_bt<0><<<dim3(12, 512), 256, 0, stream>>>(xw, qkvT, fbias, qkv, 65536, 1536, 512);
  attn_mfma<<<2048, 256, 0, stream>>>(qkv, tau, tbl, Obuf);
  gemm_bt<0><<<dim3(4, 512), 256, 0, stream>>>(Obuf, pwT, proj_b, projb, 65536, 512, 512);
  ln1_kernel<<<65536, 256, 0, stream>>>(x, projb, n1g, n1b, x1b);
  // MLP in 2 row-chunks of 32768 (hidden buffer 128 MiB)
  for (int c2 = 0; c2 < 2; c2++) {
    const unsigned short* a = x1b + (size_t)c2 * 32768 * 512;
    unsigned short* h2p = h2b + (size_t)c2 * 32768 * 512;
    gemm_bt<1><<<dim3(16, 256), 256, 0, stream>>>(a, m1T, mlp_b1, hbuf, 32768, 2048, 512);
    gemm_bt<0><<<dim3(4, 256), 256, 0, stream>>>(hbuf, m2T, mlp_b2, h2p, 32768, 512, 2048);
  }
  ln2_kernel<<<65536, 256, 0, stream>>>(x1b, h2b, n2g, n2b, out);
}